// Round 6
// baseline (218.539 us; speedup 1.0000x reference)
//
#include <hip/hip_runtime.h>
#include <hip/hip_bf16.h>

#define BB 4
#define LL 2048
#define HH 8
#define EE 64
#define SK 40
#define NT 40
#define BH (BB*HH)
#define NCH 128
#define CLEN (LL/NCH)   // 16
#define KS 64           // keys per split
#define NS (LL/KS)      // 32 splits
#define NQW 10          // queries per wave (4 waves * 10 = 40)

__device__ __forceinline__ size_t ro(int b, int l, int h) {
    return ((size_t)(b*LL + l)*HH + h)*EE;
}
__device__ __forceinline__ float bcast(float x, int sl) {
    return __uint_as_float(__builtin_amdgcn_readlane(__float_as_uint(x), sl));
}

// ---------------- Kernel 1: sparsity = max_s(q.k_samp) - mean_s(q.k_samp) ----------------
// one wave per (b,h,l); XCD-swizzled (bh&7 == bid&7). LDS-free: group g (16 lanes)
// handles samples 4i+g via bpermute row-broadcast + f4 gather + intra-group shfl reduce.
__global__ __launch_bounds__(256) void k_spars(const float* __restrict__ q,
                                               const float* __restrict__ k,
                                               const int* __restrict__ samp,
                                               float* __restrict__ spars)
{
    int bid = blockIdx.x;
    int w    = threadIdx.x >> 6;
    int lane = threadIdx.x & 63;
    int bh = (((bid >> 3) & 3) << 3) | (bid & 7);
    int l  = (bid >> 5) * 4 + w;
    int b = bh >> 3, h = bh & 7;
    int c = lane & 15, g = lane >> 4;

    int sidx = (lane < SK) ? samp[l*SK + lane] : 0;
    const float4 q4 = ((const float4*)(q + ro(b, l, h)))[c];
    const float* kbase = k + ((size_t)b*LL*HH + h)*EE;   // + row*HH*EE

    float m = -INFINITY, ssum = 0.f;
    #pragma unroll
    for (int i = 0; i < SK/4; ++i) {
        int s = 4*i + g;
        int row = __shfl(sidx, s, 64);
        float4 k4 = ((const float4*)(kbase + (size_t)row*(HH*EE)))[c];
        float p = k4.x*q4.x + k4.y*q4.y + k4.z*q4.z + k4.w*q4.w;
        #pragma unroll
        for (int off = 1; off <= 8; off <<= 1) p += __shfl_xor(p, off, 64);
        m = fmaxf(m, p);
        ssum += p;
    }
    m = fmaxf(m, __shfl_xor(m, 16, 64));
    m = fmaxf(m, __shfl_xor(m, 32, 64));
    ssum += __shfl_xor(ssum, 16, 64);
    ssum += __shfl_xor(ssum, 32, 64);
    if (lane == 0) spars[bh*LL + l] = m - ssum * (1.0f/SK);
}

// ---------------- Kernel 2: per-(b,h) top-40 + sel map -------------------------------------
__global__ __launch_bounds__(256) void k_topk(const float* __restrict__ spars,
                                              int* __restrict__ topidx,
                                              signed char* __restrict__ sel)
{
    __shared__ float wv[4];
    __shared__ int   wi[4];
    __shared__ int   top[NT];
    int bh = blockIdx.x, t = threadIdx.x, w = t >> 6, lane = t & 63;

    float r[8];
    #pragma unroll
    for (int i = 0; i < 8; ++i) r[i] = spars[bh*LL + i*256 + t];

    for (int n = 0; n < NT; ++n) {
        float bv = r[0]; int bi = t;
        #pragma unroll
        for (int i = 1; i < 8; ++i)
            if (r[i] > bv) { bv = r[i]; bi = i*256 + t; }
        #pragma unroll
        for (int off = 32; off; off >>= 1) {
            float ov = __shfl_xor(bv, off, 64);
            int   oi = __shfl_xor(bi, off, 64);
            if (ov > bv || (ov == bv && oi < bi)) { bv = ov; bi = oi; }
        }
        if (lane == 0) { wv[w] = bv; wi[w] = bi; }
        __syncthreads();
        float gv = wv[0]; int gi = wi[0];
        #pragma unroll
        for (int j = 1; j < 4; ++j) {
            float ov = wv[j]; int oi = wi[j];
            if (ov > gv || (ov == gv && oi < gi)) { gv = ov; gi = oi; }
        }
        if (t == 0) { top[n] = gi; topidx[bh*NT + n] = gi; }
        if ((gi & 255) == t) {
            int slot = gi >> 8;
            #pragma unroll
            for (int i = 0; i < 8; ++i) if (i == slot) r[i] = -INFINITY;
        }
        __syncthreads();
    }

    for (int l2 = t; l2 < LL; l2 += 256) sel[bh*LL + l2] = -1;
    __syncthreads();
    if (t < NT) sel[bh*LL + top[t]] = (signed char)t;
}

// ---------------- Kernel 3a: split-K flash attention, register-tiled -----------------------
__global__ __launch_bounds__(256) void k_attn_split(const float* __restrict__ q,
                                                    const float* __restrict__ k,
                                                    const float* __restrict__ v,
                                                    const int* __restrict__ topidx,
                                                    float* __restrict__ pm,
                                                    float* __restrict__ pl,
                                                    __hip_bfloat16* __restrict__ pO)
{
    __shared__ float KT[EE][KS+1];
    __shared__ float Vs[KS][EE];
    __shared__ int   tix[NT];
    int bh = blockIdx.x >> 5, split = blockIdx.x & 31;
    int b = bh >> 3, h = bh & 7;
    int base = split * KS;
    int t = threadIdx.x, w = t >> 6, lane = t & 63;

    if (t < NT) tix[t] = topidx[bh*NT + t];
    __syncthreads();

    int rr = t >> 4, c4 = t & 15;
    #pragma unroll
    for (int p = 0; p < 4; ++p) {
        int kr = p*16 + rr;
        const float4* krow = (const float4*)(k + ro(b, base + kr, h));
        float4 x = krow[c4];
        KT[c4*4+0][kr] = x.x; KT[c4*4+1][kr] = x.y;
        KT[c4*4+2][kr] = x.z; KT[c4*4+3][kr] = x.w;
        const float4* vrow = (const float4*)(v + ro(b, base + kr, h));
        ((float4*)&Vs[kr][0])[c4] = vrow[c4];
    }

    float qreg[NQW]; int jn[NQW];
    #pragma unroll
    for (int r = 0; r < NQW; ++r) {
        int ti = tix[w*NQW + r];
        jn[r] = min(KS, ti - base + 1);
        qreg[r] = q[ro(b, ti, h) + lane] * 0.125f;
    }
    __syncthreads();

    float S[NQW];
    #pragma unroll
    for (int r = 0; r < NQW; ++r) S[r] = 0.f;
    for (int e0 = 0; e0 < EE; e0 += 16) {
        #pragma unroll
        for (int j = 0; j < 16; ++j) {
            int e = e0 + j;
            float ke = KT[e][lane];
            #pragma unroll
            for (int r = 0; r < NQW; ++r)
                S[r] = fmaf(ke, bcast(qreg[r], e), S[r]);
        }
    }

    float P[NQW], mloc[NQW], lloc[NQW];
    #pragma unroll
    for (int r = 0; r < NQW; ++r) {
        float s = (lane < jn[r]) ? S[r] : -INFINITY;
        float m = s;
        #pragma unroll
        for (int off = 32; off; off >>= 1) m = fmaxf(m, __shfl_xor(m, off, 64));
        bool act = jn[r] > 0;
        float p = act ? __expf(s - m) : 0.f;
        float ls = p;
        #pragma unroll
        for (int off = 32; off; off >>= 1) ls += __shfl_xor(ls, off, 64);
        P[r] = p; mloc[r] = act ? m : -INFINITY; lloc[r] = act ? ls : 0.f;
    }

    float O[NQW];
    #pragma unroll
    for (int r = 0; r < NQW; ++r) O[r] = 0.f;
    for (int k0 = 0; k0 < KS; k0 += 16) {
        #pragma unroll
        for (int j = 0; j < 16; ++j) {
            int kk = k0 + j;
            float ve = Vs[kk][lane];
            #pragma unroll
            for (int r = 0; r < NQW; ++r)
                O[r] = fmaf(ve, bcast(P[r], kk), O[r]);
        }
    }

    #pragma unroll
    for (int r = 0; r < NQW; ++r) {
        int n = w*NQW + r;
        size_t idx = (size_t)(bh*NT + n)*NS + split;
        if (lane == 0) { pm[idx] = mloc[r]; pl[idx] = lloc[r]; }
        pO[idx*EE + lane] = __float2bfloat16(O[r]);
    }
}

// ---------------- Kernel 3b: combine split partials -> upd ---------------------------------
__global__ __launch_bounds__(256) void k_attn_comb(const float* __restrict__ pm,
                                                   const float* __restrict__ pl,
                                                   const __hip_bfloat16* __restrict__ pO,
                                                   float* __restrict__ upd)
{
    int wid  = (blockIdx.x * blockDim.x + threadIdx.x) >> 6;
    int lane = threadIdx.x & 63;
    float pmv = (lane < NS) ? pm[(size_t)wid*NS + lane] : -INFINITY;
    float plv = (lane < NS) ? pl[(size_t)wid*NS + lane] : 0.f;
    float M = pmv;
    #pragma unroll
    for (int off = 32; off; off >>= 1) M = fmaxf(M, __shfl_xor(M, off, 64));
    float sc = (lane < NS && pmv > -INFINITY) ? __expf(pmv - M) : 0.f;
    float L = plv * sc;
    #pragma unroll
    for (int off = 32; off; off >>= 1) L += __shfl_xor(L, off, 64);
    float O = 0.f;
    for (int s = 0; s < NS; ++s) {
        float w = bcast(sc, s);
        O += __bfloat162float(pO[((size_t)wid*NS + s)*EE + lane]) * w;
    }
    upd[(size_t)wid*EE + lane] = O / L;
}

// ---------------- Kernel 4a: per-chunk sums of v (float4, 4 rows in flight) ----------------
__global__ __launch_bounds__(256) void k_csum(const float* __restrict__ v,
                                              float* __restrict__ csum)
{
    int wid  = (blockIdx.x * blockDim.x + threadIdx.x) >> 6;   // chunk id
    int lane = threadIdx.x & 63;
    int bh = wid / NCH, cch = wid - bh*NCH;
    int b = bh >> 3, h = bh & 7;
    int r2 = lane >> 4, c4 = lane & 15;
    int l0 = cch * CLEN;
    float4 s4 = {0.f, 0.f, 0.f, 0.f};
    #pragma unroll
    for (int i = 0; i < CLEN/4; ++i) {
        float4 x = ((const float4*)(v + ro(b, l0 + i*4 + r2, h)))[c4];
        s4.x += x.x; s4.y += x.y; s4.z += x.z; s4.w += x.w;
    }
    #pragma unroll
    for (int off = 16; off <= 32; off <<= 1) {
        s4.x += __shfl_xor(s4.x, off, 64);
        s4.y += __shfl_xor(s4.y, off, 64);
        s4.z += __shfl_xor(s4.z, off, 64);
        s4.w += __shfl_xor(s4.w, off, 64);
    }
    if (r2 == 0) ((float4*)(csum + ((size_t)bh*NCH + cch)*EE))[c4] = s4;
}

// ---------------- Kernel 4b: per-bh exclusive prefix over chunks (LDS scan) ----------------
__global__ __launch_bounds__(256) void k_pfx(float* __restrict__ csum)
{
    __shared__ float buf[NCH*EE];    // 32 KB
    __shared__ float gs[4*EE];
    int bh = blockIdx.x, t = threadIdx.x;
    int e = t & 63, g = t >> 6;

    for (int i = t; i < NCH*EE; i += 256) buf[i] = csum[(size_t)bh*NCH*EE + i];
    __syncthreads();

    float s = 0.f;
    for (int c = g*32; c < g*32+32; ++c) s += buf[c*EE + e];
    gs[g*EE + e] = s;
    __syncthreads();

    float run = 0.f;
    for (int j = 0; j < g; ++j) run += gs[j*EE + e];
    for (int c = g*32; c < g*32+32; ++c) {
        float x = buf[c*EE + e];
        buf[c*EE + e] = run;
        run += x;
    }
    __syncthreads();

    for (int i = t; i < NCH*EE; i += 256) csum[(size_t)bh*NCH*EE + i] = buf[i];
}

// ---------------- Kernel 4c: cumsum + scatter + write (float4; 4 chunks per wave) ----------
__global__ __launch_bounds__(256) void k_out(const float* __restrict__ v,
                                             const float* __restrict__ csum,
                                             const signed char* __restrict__ sel,
                                             const float* __restrict__ upd,
                                             float* __restrict__ out)
{
    int wid  = (blockIdx.x * blockDim.x + threadIdx.x) >> 6;   // 0..BH*NCH/4-1
    int lane = threadIdx.x & 63;
    int bh = wid / (NCH/4), wc = wid - bh*(NCH/4);
    int b = bh >> 3, h = bh & 7;
    int g = lane >> 4, c4 = lane & 15;
    int cch = wc*4 + g;
    int l0 = cch * CLEN;

    float4 run = ((const float4*)(csum + ((size_t)bh*NCH + cch)*EE))[c4];
    for (int i = 0; i < CLEN; ++i) {
        int l = l0 + i;
        float4 x = ((const float4*)(v + ro(b, l, h)))[c4];
        run.x += x.x; run.y += x.y; run.z += x.z; run.w += x.w;
        int sn = sel[bh*LL + l];
        float4 o = run;
        if (sn >= 0) o = ((const float4*)(upd + ((size_t)bh*NT + sn)*EE))[c4];
        ((float4*)(out + ro(b, l, h)))[c4] = o;
    }
}

// ---------------- Fallback attention (tiny ws) ---------------------------------------------
__global__ __launch_bounds__(256) void k_attn_old(const float* __restrict__ q,
                                                  const float* __restrict__ k,
                                                  const float* __restrict__ v,
                                                  const int* __restrict__ topidx,
                                                  float* __restrict__ upd)
{
    __shared__ float sc[LL];
    __shared__ float red[256];
    __shared__ float part[4][EE];
    int bh = blockIdx.x / NT, n = blockIdx.x % NT;
    int b = bh >> 3, h = bh & 7;
    int ti = topidx[bh*NT + n];
    int t = threadIdx.x, w = t >> 6, lane = t & 63;

    float qe = q[ro(b, ti, h) + lane];
    for (int j = w; j <= ti; j += 4) {
        float kv = k[ro(b, j, h) + lane];
        float p = qe * kv;
        #pragma unroll
        for (int off = 32; off; off >>= 1) p += __shfl_xor(p, off, 64);
        if (lane == 0) sc[j] = p * 0.125f;
    }
    __syncthreads();
    float m = -1e30f;
    for (int j = t; j <= ti; j += 256) m = fmaxf(m, sc[j]);
    red[t] = m; __syncthreads();
    for (int s2 = 128; s2; s2 >>= 1) { if (t < s2) red[t] = fmaxf(red[t], red[t+s2]); __syncthreads(); }
    m = red[0]; __syncthreads();
    float ssum = 0.f;
    for (int j = t; j <= ti; j += 256) { float p = __expf(sc[j] - m); sc[j] = p; ssum += p; }
    red[t] = ssum; __syncthreads();
    for (int s2 = 128; s2; s2 >>= 1) { if (t < s2) red[t] += red[t+s2]; __syncthreads(); }
    float inv = 1.0f / red[0];
    float acc = 0.f;
    for (int j = w; j <= ti; j += 4) acc += sc[j] * v[ro(b, j, h) + lane];
    part[w][lane] = acc;
    __syncthreads();
    if (w == 0) {
        float r = (part[0][lane] + part[1][lane] + part[2][lane] + part[3][lane]) * inv;
        upd[((size_t)bh*NT + n)*EE + lane] = r;
    }
}

extern "C" void kernel_launch(void* const* d_in, const int* in_sizes, int n_in,
                              void* d_out, int out_size, void* d_ws, size_t ws_size,
                              hipStream_t stream) {
    const float* q = (const float*)d_in[0];
    const float* k = (const float*)d_in[1];
    const float* v = (const float*)d_in[2];
    const int* samp = (const int*)d_in[3];
    float* out = (float*)d_out;

    char* ws = (char*)d_ws;
    float*          spars  = (float*)(ws);
    float*          pm     = (float*)(ws);                      // aliases spars (dead after topk)
    int*            topidx = (int*)  (ws + 262144);
    signed char*    sel    = (signed char*)(ws + 262144 + 8192);
    float*          upd    = (float*)(ws + 262144 + 8192 + 65536);
    float*          pl     = (float*)(ws + 262144 + 8192 + 65536 + 327680);
    char*           pObase =          ws + 262144 + 8192 + 65536 + 327680 + 163840;
    __hip_bfloat16* pO     = (__hip_bfloat16*)pObase;
    float*          csum   = (float*)pObase;                    // aliases pO (dead after comb)
    size_t full_need = 262144 + 8192 + 65536 + 327680 + 163840 + (size_t)BH*NT*NS*EE*2; // 6.07 MB

    k_spars<<<BH*LL/4, 256, 0, stream>>>(q, k, samp, spars);
    k_topk <<<BH,      256, 0, stream>>>(spars, topidx, sel);
    if (ws_size >= full_need) {
        k_attn_split<<<BH*NS, 256, 0, stream>>>(q, k, v, topidx, pm, pl, pO);
        k_attn_comb <<<BH*NT/4, 256, 0, stream>>>(pm, pl, pO, upd);
    } else {
        k_attn_old<<<BH*NT, 256, 0, stream>>>(q, k, v, topidx, upd);
    }
    k_csum<<<BH*NCH/4,  256, 0, stream>>>(v, csum);
    k_pfx <<<BH,        256, 0, stream>>>(csum);
    k_out <<<BH*NCH/16, 256, 0, stream>>>(v, csum, sel, upd, out);
}